// Round 1
// baseline (610.915 us; speedup 1.0000x reference)
//
#include <hip/hip_runtime.h>
#include <hip/hip_cooperative_groups.h>
#include <math.h>

namespace cg = cooperative_groups;

#define NN   20000
#define EE   320000
#define ETOT 340000
#define FIN  128
#define HH   4
#define CC   64
#define HC   256
#define GG   64
#define BN_EPS 1e-5f
#define S1   384   // BcatT1 cols: 256 (W1 perm) + 64 (Wskip) + 8 (es/ed) + 56 pad
#define S2   320   // BcatT2 cols: 256 (W2 perm) + 8 (es/ed) + 56 pad
#define NBUCK 64   // BN-stats buckets
#define MAXDEG 64  // fixed-stride CSR row; P(Poisson(16)+1 >= 64) ~ 1e-22, fixed seed
#define EBK  1329  // ceil(ETOT/256)

typedef _Float16 v8h __attribute__((ext_vector_type(8)));
typedef _Float16 v4h __attribute__((ext_vector_type(4)));
typedef float    v4f __attribute__((ext_vector_type(4)));

__device__ __forceinline__ unsigned short f2bf(float f) {
    unsigned u = __float_as_uint(f);
    unsigned r = (u + 0x7FFF + ((u >> 16) & 1)) >> 16;   // RNE
    return (unsigned short)r;
}
__device__ __forceinline__ float bf2f(unsigned short u) {
    return __uint_as_float((unsigned)u << 16);
}
__device__ __forceinline__ float gelu_exact(float v) {
    return 0.5f * v * (1.f + erff(v * 0.70710678118654752f));
}

struct MegaParams {
    const float* x;
    const float* W1; const float* as1; const float* ad1; const float* b1;
    const float* Wskip; const float* bskip; const float* g1; const float* be1;
    const float* W2; const float* as2; const float* ad2; const float* b2;
    const float* g2; const float* be2;
    const int* ei; const int* bidx;
    float* out;
    unsigned short* h4b;
    float4* es4; float4* ed4;
    float* skip; float* gout; float* hmid;
    _Float16* BT1; _Float16* BT2;
    int* csr; int* gstart; int* deg;
    float* sbuck1; float* sbuck2;
};

// ---- GEMM tile unit: identical math to the previous gemm_mfma / gemm_mfma_bn ----
template<int NCB, bool BN>
__device__ __forceinline__ void gemm_unit(int u,
        const float* __restrict__ A, const float* __restrict__ skipIn,
        float* __restrict__ hmid, const float* sscale, const float* sshift,
        const _Float16* __restrict__ BT, int M, int K,
        unsigned short* __restrict__ h4b, float* __restrict__ skipO,
        float* __restrict__ esf, float* __restrict__ edf, int escol0,
        _Float16 (*sA)[40], _Float16 (*sBT)[40], int t) {
    const int COLT = 2 * NCB * 16;
    int tile = u & 1;
    int col0 = tile * COLT;
    int row0 = (u >> 1) * 32;
    int wave = t >> 6, lane = t & 63;
    int l15 = lane & 15, quad = lane >> 4;
    int rb  = wave & 1;
    int cb0 = (wave >> 1) * NCB;
    v4f acc[NCB] = {};
    for (int k0 = 0; k0 < K; k0 += 32) {
        {   // stage A (optionally fused BN1+skip+GELU), one float4 per thread
            int r = t >> 3, c4 = t & 7;
            int gr = row0 + r;
            int cb = k0 + c4 * 4;
            float vv[4] = {0.f, 0.f, 0.f, 0.f};
            if (gr < M) {
                if constexpr (BN) {
                    float4 q = *(const float4*)&A[(size_t)gr * K + cb];
                    float4 p = *(const float4*)&skipIn[(size_t)gr * K + cb];
                    float qa[4] = {q.x, q.y, q.z, q.w};
                    float pa[4] = {p.x, p.y, p.z, p.w};
                    #pragma unroll
                    for (int uu = 0; uu < 4; ++uu)
                        vv[uu] = gelu_exact(qa[uu] * sscale[cb + uu] + sshift[cb + uu] + pa[uu]);
                    if (tile == 0)
                        *(float4*)&hmid[(size_t)gr * K + cb] =
                            make_float4(vv[0], vv[1], vv[2], vv[3]);
                } else {
                    float4 v0 = *(const float4*)&A[(size_t)gr * K + cb];
                    vv[0] = v0.x; vv[1] = v0.y; vv[2] = v0.z; vv[3] = v0.w;
                }
            }
            v4h hv;
            hv[0] = (_Float16)vv[0]; hv[1] = (_Float16)vv[1];
            hv[2] = (_Float16)vv[2]; hv[3] = (_Float16)vv[3];
            *(v4h*)&sA[r][c4 * 4] = hv;
        }
        for (int j = t; j < COLT * 4; j += 256) {
            int c = j >> 2, s = j & 3;
            *(v8h*)&sBT[c][s * 8] = *(const v8h*)&BT[(size_t)(col0 + c) * K + k0 + s * 8];
        }
        __syncthreads();
        v8h af = *(const v8h*)&sA[rb * 16 + l15][quad * 8];
        #pragma unroll
        for (int c = 0; c < NCB; ++c) {
            v8h bf = *(const v8h*)&sBT[(cb0 + c) * 16 + l15][quad * 8];
            acc[c] = __builtin_amdgcn_mfma_f32_16x16x32_f16(af, bf, acc[c], 0, 0, 0);
        }
        __syncthreads();
    }
    // epilogue: D[row=quad*4+reg][col=l15] per 16x16 frag (verified mapping)
    #pragma unroll
    for (int c = 0; c < NCB; ++c) {
        int gcol = col0 + (cb0 + c) * 16 + l15;
        #pragma unroll
        for (int reg = 0; reg < 4; ++reg) {
            int gr = row0 + rb * 16 + quad * 4 + reg;
            if (gr >= M) continue;
            float v = acc[c][reg];
            if (gcol < 256) {
                h4b[(size_t)gr * HC + gcol] = f2bf(v);
            } else if (skipO != nullptr && gcol < 320) {
                skipO[(size_t)gr * CC + (gcol - 256)] = v;
            } else if (gcol >= escol0 && gcol < escol0 + 8) {
                if (gcol < escol0 + 4) esf[gr * 4 + (gcol - escol0)] = v;
                else                   edf[gr * 4 + (gcol - escol0 - 4)] = v;
            }
        }
    }
}

// ---- aggregation unit: identical math to the previous aggr_kernel -------------
__device__ __forceinline__ void edge_acc(const float4 esv, const ushort4 hv,
        const float4 edn, float4& acc, float4& ssum) {
    float e0 = esv.x + edn.x; e0 = fmaxf(e0, 0.2f * e0); float w0 = __expf(e0);
    float e1 = esv.y + edn.y; e1 = fmaxf(e1, 0.2f * e1); float w1 = __expf(e1);
    float e2 = esv.z + edn.z; e2 = fmaxf(e2, 0.2f * e2); float w2 = __expf(e2);
    float e3 = esv.w + edn.w; e3 = fmaxf(e3, 0.2f * e3); float w3 = __expf(e3);
    acc.x += w0 * bf2f(hv.x); ssum.x += w0;
    acc.y += w1 * bf2f(hv.y); ssum.y += w1;
    acc.z += w2 * bf2f(hv.z); ssum.z += w2;
    acc.w += w3 * bf2f(hv.w); ssum.w += w3;
}

__device__ __forceinline__ void aggr_unit(int u, const unsigned short* __restrict__ h4b,
        const float4* __restrict__ es4, const float4* __restrict__ ed4,
        const int* __restrict__ deg, const int* __restrict__ csr_src,
        const float* __restrict__ bias, float* __restrict__ out,
        float* __restrict__ sbuck, float* sls, int t) {
    int wave = t >> 6, lane = t & 63;
    int n = u * 4 + wave;
    float4 edn = ed4[n];
    float4 acc = make_float4(0.f, 0.f, 0.f, 0.f);
    float4 ssum = make_float4(0.f, 0.f, 0.f, 0.f);
    int dn = deg[n];
    dn = (dn < MAXDEG) ? dn : MAXDEG;      // memory safety; never triggers
    int beg = n * MAXDEG, end = beg + dn;
    int j = beg;
    for (; j + 4 <= end; j += 4) {
        int s0 = csr_src[j + 0];
        int s1 = csr_src[j + 1];
        int s2 = csr_src[j + 2];
        int s3 = csr_src[j + 3];
        float4 E0 = es4[s0];
        float4 E1 = es4[s1];
        float4 E2 = es4[s2];
        float4 E3 = es4[s3];
        ushort4 v0 = *(const ushort4*)&h4b[(size_t)s0 * HC + lane * 4];
        ushort4 v1 = *(const ushort4*)&h4b[(size_t)s1 * HC + lane * 4];
        ushort4 v2 = *(const ushort4*)&h4b[(size_t)s2 * HC + lane * 4];
        ushort4 v3 = *(const ushort4*)&h4b[(size_t)s3 * HC + lane * 4];
        edge_acc(E0, v0, edn, acc, ssum);
        edge_acc(E1, v1, edn, acc, ssum);
        edge_acc(E2, v2, edn, acc, ssum);
        edge_acc(E3, v3, edn, acc, ssum);
    }
    for (; j < end; ++j) {
        int s = csr_src[j];
        float4 E = es4[s];
        ushort4 v = *(const ushort4*)&h4b[(size_t)s * HC + lane * 4];
        edge_acc(E, v, edn, acc, ssum);
    }
    float val = 0.25f * (acc.x / (ssum.x + 1e-16f) + acc.y / (ssum.y + 1e-16f) +
                         acc.z / (ssum.z + 1e-16f) + acc.w / (ssum.w + 1e-16f)) + bias[lane];
    out[n * CC + lane] = val;
    float (*ls)[64] = (float (*)[64])sls;
    float (*lq)[64] = (float (*)[64])(sls + 256);
    ls[wave][lane] = val;
    lq[wave][lane] = val * val;
    __syncthreads();
    if (wave == 0) {
        float s = ls[0][lane] + ls[1][lane] + ls[2][lane] + ls[3][lane];
        float q = lq[0][lane] + lq[1][lane] + lq[2][lane] + lq[3][lane];
        int bk = (u & (NBUCK - 1)) * 128;
        atomicAdd(&sbuck[bk + lane], s);
        atomicAdd(&sbuck[bk + 64 + lane], q);
    }
    __syncthreads();   // ls/lq reused next grid-stride iteration
}

// ====== ONE persistent cooperative kernel: all 6 former dispatches =============
// P0 pre | sync | P1 gemm1+CSR-fill | sync | P2 aggr1 | sync |
// P3 gemm2(BN-fused) | sync | P4 aggr2 | sync | P5 bnapply2+pool
__global__ __launch_bounds__(256) void mega(MegaParams P) {
    cg::grid_group grid = cg::this_grid();
    __shared__ __align__(16) unsigned char smem[17920];   // max phase: sA32 + sBT192 (x80B)
    __shared__ float sS[64], sH[64];
    __shared__ int gi[4];
    int t = threadIdx.x;
    int nG = gridDim.x;

    // ---------------- P0: gbound | BcatT1 | BcatT2 | zero out/deg/sbuck ----------
    for (int u = blockIdx.x; u < 510; u += nG) {
        if (u < 79) {
            int i = u * 256 + t;
            if (i < NN) {
                int cur = P.bidx[i];
                if (i == 0) { for (int g = 0; g <= cur; ++g) P.gstart[g] = 0; }
                else { int prev = P.bidx[i - 1]; for (int g = prev + 1; g <= cur; ++g) P.gstart[g] = i; }
                if (i == NN - 1) { for (int g = cur + 1; g <= GG; ++g) P.gstart[g] = NN; }
            }
        } else if (u < 271) {
            int i = (u - 79) * 256 + t;          // i < S1*FIN = 49152; BT1[col][k]
            int col = i >> 7, k = i & 127;
            float v;
            if (col < 256) {
                v = P.W1[k * 256 + (col & 3) * 64 + (col >> 2)];
            } else if (col < 320) {
                v = P.Wskip[k * 64 + (col - 256)];
            } else if (col < 328) {
                int kk = col - 320, h = kk & 3;
                const float* av = (kk < 4 ? P.as1 : P.ad1) + h * 64;
                const float* wr = P.W1 + k * 256 + h * 64;
                float sdot = 0.f;
                #pragma unroll 8
                for (int c = 0; c < 64; ++c) sdot += wr[c] * av[c];
                v = sdot;
            } else v = 0.f;
            P.BT1[i] = (_Float16)v;
        } else if (u < 351) {
            int i = (u - 271) * 256 + t;         // i < S2*CC = 20480; BT2[col][k]
            int col = i >> 6, k = i & 63;
            float v;
            if (col < 256) {
                v = P.W2[k * 256 + (col & 3) * 64 + (col >> 2)];
            } else if (col < 264) {
                int kk = col - 256, h = kk & 3;
                const float* av = (kk < 4 ? P.as2 : P.ad2) + h * 64;
                const float* wr = P.W2 + k * 256 + h * 64;
                float sdot = 0.f;
                #pragma unroll 8
                for (int c = 0; c < 64; ++c) sdot += wr[c] * av[c];
                v = sdot;
            } else v = 0.f;
            P.BT2[i] = (_Float16)v;
        } else if (u < 367) {
            int i = (u - 351) * 256 + t;         // GG*CC = 4096
            P.out[i] = 0.f;
        } else if (u < 446) {
            int i = (u - 367) * 256 + t;
            if (i < NN) P.deg[i] = 0;
        } else if (u < 478) {
            int i = (u - 446) * 256 + t;         // NBUCK*128 = 8192
            P.sbuck1[i] = 0.f;
        } else {
            int i = (u - 478) * 256 + t;
            P.sbuck2[i] = 0.f;
        }
    }
    grid.sync();

    _Float16 (*sA)[40]  = (_Float16 (*)[40])smem;
    _Float16 (*sBT)[40] = (_Float16 (*)[40])(smem + 32 * 40 * 2);
    float* sls = (float*)smem;

    // ---------------- P1: layer-1 GEMM tiles + degree-count/CSR-fill -------------
    for (int u = blockIdx.x; u < 1250 + EBK; u += nG) {
        if (u < 1250) {
            gemm_unit<6, false>(u, P.x, nullptr, nullptr, nullptr, nullptr,
                P.BT1, NN, FIN, P.h4b, P.skip, (float*)P.es4, (float*)P.ed4, 320,
                sA, sBT, t);
        } else {
            int i = (u - 1250) * 256 + t;
            if (i < ETOT) {
                int s, d;
                if (i < EE) { s = P.ei[i]; d = P.ei[EE + i]; } else { s = i - EE; d = i - EE; }
                int pp = atomicAdd(&P.deg[d], 1);
                if (pp < MAXDEG) P.csr[d * MAXDEG + pp] = s;   // overflow never triggers
            }
        }
    }
    grid.sync();

    // ---------------- P2: layer-1 aggregation (+bucketed BN stats) ----------------
    for (int u = blockIdx.x; u < 5000; u += nG)
        aggr_unit(u, P.h4b, P.es4, P.ed4, P.deg, P.csr, P.b1, P.gout, P.sbuck1, sls, t);
    grid.sync();

    // ---------------- P3: layer-2 GEMM with fused BN1+skip+GELU A-staging ---------
    {
        float* tmp = (float*)smem;               // overlaps sA; dead after 2nd sync
        if (t < 128) {
            float s = 0.f;
            #pragma unroll 16
            for (int k = 0; k < NBUCK; ++k) s += P.sbuck1[k * 128 + t];
            tmp[t] = s;
        }
        __syncthreads();
        if (t < 64) {
            float mu  = tmp[t] * (1.f / NN);
            float var = tmp[64 + t] * (1.f / NN) - mu * mu;
            float inv = rsqrtf(var + BN_EPS) * P.g1[t];
            sS[t] = inv;
            sH[t] = P.be1[t] + P.bskip[t] - mu * inv;
        }
        __syncthreads();
    }
    for (int u = blockIdx.x; u < 1250; u += nG)
        gemm_unit<5, true>(u, P.gout, P.skip, P.hmid, sS, sH,
            P.BT2, NN, CC, P.h4b, nullptr, (float*)P.es4, (float*)P.ed4, 256,
            sA, sBT, t);
    grid.sync();

    // ---------------- P4: layer-2 aggregation ------------------------------------
    for (int u = blockIdx.x; u < 5000; u += nG)
        aggr_unit(u, P.h4b, P.es4, P.ed4, P.deg, P.csr, P.b2, P.gout, P.sbuck2, sls, t);
    grid.sync();

    // ---------------- P5: BN2 apply + GELU + fused mean-pool ---------------------
    {
        float* tmp = (float*)smem;
        if (t < 128) {
            float s = 0.f;
            #pragma unroll 16
            for (int k = 0; k < NBUCK; ++k) s += P.sbuck2[k * 128 + t];
            tmp[t] = s;
        }
        __syncthreads();
        if (t < 64) {
            float mu  = tmp[t] * (1.f / NN);
            float var = tmp[64 + t] * (1.f / NN) - mu * mu;
            sS[t] = mu;
            sH[t] = rsqrtf(var + BN_EPS) * P.g2[t];
        }
        __syncthreads();
        float (*ls)[64] = (float (*)[64])smem;   // tmp dead; reuse
        for (int u = blockIdx.x; u < 5000; u += nG) {
            int i = u * 256 + t;
            int ch = i & 63;
            int wave = t >> 6;
            int n = i >> 6;
            float v = (P.gout[i] - sS[ch]) * sH[ch] + P.be2[ch] + P.hmid[i];
            v = gelu_exact(v);
            int gg = P.bidx[n];
            int cnt = P.gstart[gg + 1] - P.gstart[gg];
            ls[wave][ch] = v * (1.f / (float)cnt);
            if (ch == 0) gi[wave] = gg;
            __syncthreads();
            if (wave == 0) {
                if (gi[0] == gi[1] && gi[1] == gi[2] && gi[2] == gi[3]) {
                    float s4 = ls[0][ch] + ls[1][ch] + ls[2][ch] + ls[3][ch];
                    atomicAdd(&P.out[gi[0] * CC + ch], s4);
                } else {
                    #pragma unroll
                    for (int w2 = 0; w2 < 4; ++w2)
                        atomicAdd(&P.out[gi[w2] * CC + ch], ls[w2][ch]);
                }
            }
            __syncthreads();
        }
    }
}

extern "C" void kernel_launch(void* const* d_in, const int* in_sizes, int n_in,
                              void* d_out, int out_size, void* d_ws, size_t ws_size,
                              hipStream_t stream) {
    MegaParams P;
    P.x      = (const float*)d_in[0];
    P.W1     = (const float*)d_in[1];
    P.as1    = (const float*)d_in[2];
    P.ad1    = (const float*)d_in[3];
    P.b1     = (const float*)d_in[4];
    P.Wskip  = (const float*)d_in[5];
    P.bskip  = (const float*)d_in[6];
    P.g1     = (const float*)d_in[7];
    P.be1    = (const float*)d_in[8];
    P.W2     = (const float*)d_in[9];
    P.as2    = (const float*)d_in[10];
    P.ad2    = (const float*)d_in[11];
    P.b2     = (const float*)d_in[12];
    P.g2     = (const float*)d_in[13];
    P.be2    = (const float*)d_in[14];
    P.ei     = (const int*)d_in[15];
    P.bidx   = (const int*)d_in[16];
    P.out    = (float*)d_out;

    char* w = (char*)d_ws;
    size_t o = 0;
    auto alloc = [&](size_t bytes) -> void* {
        void* p = w + o;
        o = (o + bytes + 255) & ~(size_t)255;
        return p;
    };
    P.h4b  = (unsigned short*)alloc((size_t)NN * HC * 2);   // bf16 [N][C][H]
    P.es4  = (float4*)alloc((size_t)NN * 16);
    P.ed4  = (float4*)alloc((size_t)NN * 16);
    P.skip = (float*)alloc((size_t)NN * CC * 4);
    P.gout = (float*)alloc((size_t)NN * CC * 4);
    P.hmid = (float*)alloc((size_t)NN * CC * 4);
    P.BT1  = (_Float16*)alloc((size_t)S1 * FIN * 2);
    P.BT2  = (_Float16*)alloc((size_t)S2 * CC * 2);
    P.csr  = (int*)alloc((size_t)NN * MAXDEG * 4);
    P.gstart = (int*)alloc((size_t)(GG + 1) * 4);
    P.deg    = (int*)alloc((size_t)NN * 4);
    P.sbuck1 = (float*)alloc((size_t)NBUCK * 128 * 4);
    P.sbuck2 = (float*)alloc((size_t)NBUCK * 128 * 4);

    // Grid must be fully co-resident for cooperative launch; size from occupancy.
    static int gblocks = 0;
    if (gblocks == 0) {
        int nb = 0, dev = 0, cus = 0;
        hipGetDevice(&dev);
        hipDeviceGetAttribute(&cus, hipDeviceAttributeMultiprocessorCount, dev);
        hipOccupancyMaxActiveBlocksPerMultiprocessor(&nb, mega, 256, 0);
        if (cus <= 0) cus = 256;
        if (nb <= 0) nb = 1;
        long long g = (long long)nb * cus;
        if (g > 2048) g = 2048;
        gblocks = (int)g;
    }
    void* args[] = { (void*)&P };
    hipLaunchCooperativeKernel(mega, dim3(gblocks), dim3(256), args, 0, stream);
}

// Round 2
// 224.325 us; speedup vs baseline: 2.7233x; 2.7233x over previous
//
#include <hip/hip_runtime.h>
#include <math.h>

#define NN   20000
#define EE   320000
#define ETOT 340000
#define FIN  128
#define HH   4
#define CC   64
#define HC   256
#define GG   64
#define BN_EPS 1e-5f
#define S1   384   // BcatT1 cols: 256 (W1 perm) + 64 (Wskip) + 8 (es/ed) + 56 pad
#define S2   320   // BcatT2 cols: 256 (W2 perm) + 8 (es/ed) + 56 pad
#define NBUCK 128  // BN-stats buckets (10000 blocks / 128 ~ 78 adds/address)
#define MAXDEG 64  // fixed-stride CSR row; P(Poisson(16)+1 >= 64) ~ 1e-22, fixed seed

typedef _Float16 v8h __attribute__((ext_vector_type(8)));
typedef _Float16 v4h __attribute__((ext_vector_type(4)));
typedef float    v4f __attribute__((ext_vector_type(4)));

__device__ __forceinline__ unsigned short f2bf(float f) {
    unsigned u = __float_as_uint(f);
    unsigned r = (u + 0x7FFF + ((u >> 16) & 1)) >> 16;   // RNE
    return (unsigned short)r;
}
__device__ __forceinline__ float bf2f(unsigned short u) {
    return __uint_as_float((unsigned)u << 16);
}
__device__ __forceinline__ float gelu_exact(float v) {
    return 0.5f * v * (1.f + erff(v * 0.70710678118654752f));
}

// ====== pre1: gbound | BcatT1 | BcatT2 | zero out/deg/sbuck (574 blocks) ==========
__global__ __launch_bounds__(256) void pre1_kernel(
        const int* __restrict__ bidx, int* __restrict__ gstart,
        const float* __restrict__ W1, const float* __restrict__ Wskip,
        const float* __restrict__ W2,
        const float* __restrict__ as1, const float* __restrict__ ad1,
        const float* __restrict__ as2, const float* __restrict__ ad2,
        _Float16* __restrict__ BT1, _Float16* __restrict__ BT2,
        int* __restrict__ deg, float* __restrict__ sbuck1,
        float* __restrict__ sbuck2, float* __restrict__ outz) {
    int b = blockIdx.x, t = threadIdx.x;
    if (b < 79) {
        int i = b * 256 + t;
        if (i >= NN) return;
        int cur = bidx[i];
        if (i == 0) { for (int g = 0; g <= cur; ++g) gstart[g] = 0; }
        else { int prev = bidx[i - 1]; for (int g = prev + 1; g <= cur; ++g) gstart[g] = i; }
        if (i == NN - 1) { for (int g = cur + 1; g <= GG; ++g) gstart[g] = NN; }
    } else if (b < 271) {
        int i = (b - 79) * 256 + t;          // i < S1*FIN = 49152; BT1[col][k]
        int col = i >> 7, k = i & 127;
        float v;
        if (col < 256) {
            v = W1[k * 256 + (col & 3) * 64 + (col >> 2)];
        } else if (col < 320) {
            v = Wskip[k * 64 + (col - 256)];
        } else if (col < 328) {
            int kk = col - 320, h = kk & 3;
            const float* av = (kk < 4 ? as1 : ad1) + h * 64;
            const float* wr = W1 + k * 256 + h * 64;
            float s = 0.f;
            #pragma unroll 8
            for (int c = 0; c < 64; ++c) s += wr[c] * av[c];
            v = s;
        } else v = 0.f;
        BT1[i] = (_Float16)v;
    } else if (b < 351) {
        int i = (b - 271) * 256 + t;         // i < S2*CC = 20480; BT2[col][k]
        int col = i >> 6, k = i & 63;
        float v;
        if (col < 256) {
            v = W2[k * 256 + (col & 3) * 64 + (col >> 2)];
        } else if (col < 264) {
            int kk = col - 256, h = kk & 3;
            const float* av = (kk < 4 ? as2 : ad2) + h * 64;
            const float* wr = W2 + k * 256 + h * 64;
            float s = 0.f;
            #pragma unroll 8
            for (int c = 0; c < 64; ++c) s += wr[c] * av[c];
            v = s;
        } else v = 0.f;
        BT2[i] = (_Float16)v;
    } else if (b < 367) {
        int i = (b - 351) * 256 + t;         // GG*CC = 4096
        outz[i] = 0.f;
    } else if (b < 446) {
        int i = (b - 367) * 256 + t;
        if (i < NN) deg[i] = 0;
    } else if (b < 510) {
        int i = (b - 446) * 256 + t;         // NBUCK*128 = 16384
        sbuck1[i] = 0.f;
    } else {
        int i = (b - 510) * 256 + t;
        sbuck2[i] = 0.f;
    }
}

// ====== fused MFMA fp16 GEMM, 32-row blocks (+ merged count+fill blocks) ==========
template<int NCB>
__global__ __launch_bounds__(256) void gemm_mfma(const float* __restrict__ A,
        const _Float16* __restrict__ BT, int M, int K,
        unsigned short* __restrict__ h4b, float* __restrict__ skipO,
        float* __restrict__ esf, float* __restrict__ edf,
        int escol0, int ngemm, int do_fill,
        const int* __restrict__ ei, int* __restrict__ deg,
        int* __restrict__ csr) {
    int b = blockIdx.x;
    int t = threadIdx.x;
    if (do_fill && b >= ngemm) {
        int i = (b - ngemm) * 256 + t;
        if (i >= ETOT) return;
        int s, d;
        if (i < EE) { s = ei[i]; d = ei[EE + i]; } else { s = i - EE; d = i - EE; }
        int p = atomicAdd(&deg[d], 1);
        if (p < MAXDEG) csr[d * MAXDEG + p] = s;   // overflow never triggers (1e-22)
        return;
    }
    const int COLT = 2 * NCB * 16;         // 192
    __shared__ _Float16 sA[32][40];        // [row][k], 80B rows
    __shared__ _Float16 sBT[2 * NCB * 16][40];
    int tile = b & 1;
    int col0 = tile * COLT;
    int row0 = (b >> 1) * 32;
    int wave = t >> 6, lane = t & 63;
    int l15 = lane & 15, quad = lane >> 4;
    int rb  = wave & 1;                    // row-frag 0/1
    int cb0 = (wave >> 1) * NCB;           // col-frag base
    v4f acc[NCB] = {};
    for (int k0 = 0; k0 < K; k0 += 32) {
        {   // stage A: 32 rows x 32 k, fp32 -> fp16 (one float4 per thread)
            int r = t >> 3, c4 = t & 7;
            int gr = row0 + r;
            float4 v0 = make_float4(0.f, 0.f, 0.f, 0.f);
            if (gr < M) v0 = *(const float4*)&A[(size_t)gr * K + k0 + c4 * 4];
            v4h hv;
            hv[0] = (_Float16)v0.x; hv[1] = (_Float16)v0.y;
            hv[2] = (_Float16)v0.z; hv[3] = (_Float16)v0.w;
            *(v4h*)&sA[r][c4 * 4] = hv;
        }
        for (int j = t; j < COLT * 4; j += 256) {
            int c = j >> 2, s = j & 3;
            *(v8h*)&sBT[c][s * 8] = *(const v8h*)&BT[(size_t)(col0 + c) * K + k0 + s * 8];
        }
        __syncthreads();
        v8h af = *(const v8h*)&sA[rb * 16 + l15][quad * 8];
        #pragma unroll
        for (int c = 0; c < NCB; ++c) {
            v8h bf = *(const v8h*)&sBT[(cb0 + c) * 16 + l15][quad * 8];
            acc[c] = __builtin_amdgcn_mfma_f32_16x16x32_f16(af, bf, acc[c], 0, 0, 0);
        }
        __syncthreads();
    }
    // epilogue: D[row=quad*4+reg][col=l15] per 16x16 frag (verified mapping)
    #pragma unroll
    for (int c = 0; c < NCB; ++c) {
        int gcol = col0 + (cb0 + c) * 16 + l15;
        #pragma unroll
        for (int reg = 0; reg < 4; ++reg) {
            int gr = row0 + rb * 16 + quad * 4 + reg;
            if (gr >= M) continue;
            float v = acc[c][reg];
            if (gcol < 256) {
                h4b[(size_t)gr * HC + gcol] = f2bf(v);
            } else if (skipO != nullptr && gcol < 320) {
                skipO[(size_t)gr * CC + (gcol - 256)] = v;
            } else if (gcol >= escol0 && gcol < escol0 + 8) {
                if (gcol < escol0 + 4) esf[gr * 4 + (gcol - escol0)] = v;
                else                   edf[gr * 4 + (gcol - escol0 - 4)] = v;
            }
        }
    }
}

// ====== layer-2 GEMM with fused BN1+skip+GELU A-staging ===========================
template<int NCB>
__global__ __launch_bounds__(256) void gemm_mfma_bn(const float* __restrict__ gout,
        const float* __restrict__ skip, const float* __restrict__ sbuck,
        const float* __restrict__ g, const float* __restrict__ be,
        const float* __restrict__ bskip, float* __restrict__ hmid,
        const _Float16* __restrict__ BT, int M, int K,
        unsigned short* __restrict__ h4b,
        float* __restrict__ esf, float* __restrict__ edf, int escol0) {
    const int COLT = 2 * NCB * 16;         // 160
    __shared__ _Float16 sA[32][40];
    __shared__ _Float16 sBT[2 * NCB * 16][40];
    __shared__ float tmp[128];
    __shared__ float sscale[64], sshift[64];
    int t = threadIdx.x;
    int b = blockIdx.x;
    if (t < 128) {
        float s = 0.f;
        #pragma unroll 16
        for (int k = 0; k < NBUCK; ++k) s += sbuck[k * 128 + t];
        tmp[t] = s;
    }
    __syncthreads();
    if (t < 64) {
        float mu  = tmp[t] * (1.f / NN);
        float var = tmp[64 + t] * (1.f / NN) - mu * mu;
        float inv = rsqrtf(var + BN_EPS) * g[t];
        sscale[t] = inv;
        sshift[t] = be[t] + bskip[t] - mu * inv;
    }
    __syncthreads();
    int tile = b & 1;
    int col0 = tile * COLT;
    int row0 = (b >> 1) * 32;
    int wave = t >> 6, lane = t & 63;
    int l15 = lane & 15, quad = lane >> 4;
    int rb  = wave & 1;
    int cb0 = (wave >> 1) * NCB;
    v4f acc[NCB] = {};
    for (int k0 = 0; k0 < K; k0 += 32) {
        {   // stage A with fused BN1+skip+GELU: 32 rows x 32 ch, float4/thread
            int r = t >> 3, c4 = t & 7;
            int gr = row0 + r;
            int cb = k0 + c4 * 4;          // channel base
            float vv[4];
            if (gr < M) {
                float4 q = *(const float4*)&gout[(size_t)gr * CC + cb];
                float4 p = *(const float4*)&skip[(size_t)gr * CC + cb];
                float qa[4] = {q.x, q.y, q.z, q.w};
                float pa[4] = {p.x, p.y, p.z, p.w};
                #pragma unroll
                for (int u = 0; u < 4; ++u)
                    vv[u] = gelu_exact(qa[u] * sscale[cb + u] + sshift[cb + u] + pa[u]);
                if (tile == 0)
                    *(float4*)&hmid[(size_t)gr * CC + cb] =
                        make_float4(vv[0], vv[1], vv[2], vv[3]);
            } else {
                vv[0] = vv[1] = vv[2] = vv[3] = 0.f;
            }
            v4h hv;
            hv[0] = (_Float16)vv[0]; hv[1] = (_Float16)vv[1];
            hv[2] = (_Float16)vv[2]; hv[3] = (_Float16)vv[3];
            *(v4h*)&sA[r][c4 * 4] = hv;
        }
        for (int j = t; j < COLT * 4; j += 256) {
            int c = j >> 2, s = j & 3;
            *(v8h*)&sBT[c][s * 8] = *(const v8h*)&BT[(size_t)(col0 + c) * K + k0 + s * 8];
        }
        __syncthreads();
        v8h af = *(const v8h*)&sA[rb * 16 + l15][quad * 8];
        #pragma unroll
        for (int c = 0; c < NCB; ++c) {
            v8h bf = *(const v8h*)&sBT[(cb0 + c) * 16 + l15][quad * 8];
            acc[c] = __builtin_amdgcn_mfma_f32_16x16x32_f16(af, bf, acc[c], 0, 0, 0);
        }
        __syncthreads();
    }
    #pragma unroll
    for (int c = 0; c < NCB; ++c) {
        int gcol = col0 + (cb0 + c) * 16 + l15;
        #pragma unroll
        for (int reg = 0; reg < 4; ++reg) {
            int gr = row0 + rb * 16 + quad * 4 + reg;
            if (gr >= M) continue;
            float v = acc[c][reg];
            if (gcol < 256) {
                h4b[(size_t)gr * HC + gcol] = f2bf(v);
            } else if (gcol >= escol0 && gcol < escol0 + 8) {
                if (gcol < escol0 + 4) esf[gr * 4 + (gcol - escol0)] = v;
                else                   edf[gr * 4 + (gcol - escol0 - 4)] = v;
            }
        }
    }
}

// ====== aggregation + fused BN statistics (bucketed atomics) =======================
__device__ __forceinline__ void edge_acc(const float4 esv, const ushort4 hv,
        const float4 edn, float4& acc, float4& ssum) {
    float e0 = esv.x + edn.x; e0 = fmaxf(e0, 0.2f * e0); float w0 = __expf(e0);
    float e1 = esv.y + edn.y; e1 = fmaxf(e1, 0.2f * e1); float w1 = __expf(e1);
    float e2 = esv.z + edn.z; e2 = fmaxf(e2, 0.2f * e2); float w2 = __expf(e2);
    float e3 = esv.w + edn.w; e3 = fmaxf(e3, 0.2f * e3); float w3 = __expf(e3);
    acc.x += w0 * bf2f(hv.x); ssum.x += w0;
    acc.y += w1 * bf2f(hv.y); ssum.y += w1;
    acc.z += w2 * bf2f(hv.z); ssum.z += w2;
    acc.w += w3 * bf2f(hv.w); ssum.w += w3;
}

// grid = NN/2 = 10000 blocks; 2 waves per node (halved gather latency chain;
// unnormalized acc/ssum are additive so the cross-wave combine is exact).
__global__ __launch_bounds__(256) void aggr_kernel(const unsigned short* __restrict__ h4b,
        const float4* __restrict__ es4, const float4* __restrict__ ed4,
        const int* __restrict__ deg, const int* __restrict__ csr_src,
        const float* __restrict__ bias, float* __restrict__ out,
        float* __restrict__ sbuck) {
    int wave = threadIdx.x >> 6, lane = threadIdx.x & 63;
    int nodew = wave >> 1;                 // node slot 0/1 within block
    int half  = wave & 1;                  // which half of the CSR row
    int n = blockIdx.x * 2 + nodew;
    float4 edn = ed4[n];
    float4 acc = make_float4(0.f, 0.f, 0.f, 0.f);
    float4 ssum = make_float4(0.f, 0.f, 0.f, 0.f);
    int dn = deg[n];
    dn = (dn < MAXDEG) ? dn : MAXDEG;      // memory safety; never triggers
    int h0 = (dn + 1) >> 1;                // split point
    int beg = n * MAXDEG + (half ? h0 : 0);
    int end = n * MAXDEG + (half ? dn : h0);
    int j = beg;
    for (; j + 4 <= end; j += 4) {
        int s0 = csr_src[j + 0];
        int s1 = csr_src[j + 1];
        int s2 = csr_src[j + 2];
        int s3 = csr_src[j + 3];
        float4 E0 = es4[s0];
        float4 E1 = es4[s1];
        float4 E2 = es4[s2];
        float4 E3 = es4[s3];
        ushort4 v0 = *(const ushort4*)&h4b[(size_t)s0 * HC + lane * 4];
        ushort4 v1 = *(const ushort4*)&h4b[(size_t)s1 * HC + lane * 4];
        ushort4 v2 = *(const ushort4*)&h4b[(size_t)s2 * HC + lane * 4];
        ushort4 v3 = *(const ushort4*)&h4b[(size_t)s3 * HC + lane * 4];
        edge_acc(E0, v0, edn, acc, ssum);
        edge_acc(E1, v1, edn, acc, ssum);
        edge_acc(E2, v2, edn, acc, ssum);
        edge_acc(E3, v3, edn, acc, ssum);
    }
    for (; j < end; ++j) {
        int s = csr_src[j];
        float4 E = es4[s];
        ushort4 v = *(const ushort4*)&h4b[(size_t)s * HC + lane * 4];
        edge_acc(E, v, edn, acc, ssum);
    }
    __shared__ float4 sac[4][64], ssu[4][64];
    __shared__ float ls[2][64], lq[2][64];
    sac[wave][lane] = acc;
    ssu[wave][lane] = ssum;
    __syncthreads();
    if (half == 0) {
        float4 a2 = sac[wave + 1][lane];
        float4 s2 = ssu[wave + 1][lane];
        acc.x += a2.x; acc.y += a2.y; acc.z += a2.z; acc.w += a2.w;
        ssum.x += s2.x; ssum.y += s2.y; ssum.z += s2.z; ssum.w += s2.w;
        float val = 0.25f * (acc.x / (ssum.x + 1e-16f) + acc.y / (ssum.y + 1e-16f) +
                             acc.z / (ssum.z + 1e-16f) + acc.w / (ssum.w + 1e-16f)) + bias[lane];
        out[n * CC + lane] = val;
        ls[nodew][lane] = val;
        lq[nodew][lane] = val * val;
    }
    __syncthreads();
    if (wave == 0) {
        float s = ls[0][lane] + ls[1][lane];
        float q = lq[0][lane] + lq[1][lane];
        int bk = (blockIdx.x & (NBUCK - 1)) * 128;
        atomicAdd(&sbuck[bk + lane], s);
        atomicAdd(&sbuck[bk + 64 + lane], q);
    }
}

// ---------------- BN apply, layer 2 + fused mean-pool (4-node combined atomics) ----
__global__ __launch_bounds__(256) void bnapply2_kernel(const float* __restrict__ gout,
        const float* __restrict__ sbuck, const float* __restrict__ g,
        const float* __restrict__ be, const float* __restrict__ resid,
        const int* __restrict__ bidx, const int* __restrict__ gstart,
        float* __restrict__ out) {
    __shared__ float tmp[128];
    __shared__ float smu[64], sinv[64];
    __shared__ float ls[4][64];
    __shared__ int gi[4];
    int t = threadIdx.x;
    if (t < 128) {
        float s = 0.f;
        #pragma unroll 16
        for (int k = 0; k < NBUCK; ++k) s += sbuck[k * 128 + t];
        tmp[t] = s;
    }
    __syncthreads();
    if (t < 64) {
        float mu  = tmp[t] * (1.f / NN);
        float var = tmp[64 + t] * (1.f / NN) - mu * mu;
        smu[t] = mu;
        sinv[t] = rsqrtf(var + BN_EPS) * g[t];
    }
    __syncthreads();
    int i = blockIdx.x * 256 + t;
    int ch = i & 63;
    int wave = t >> 6;
    int n = i >> 6;
    float v = (gout[i] - smu[ch]) * sinv[ch] + be[ch] + resid[i];
    v = gelu_exact(v);
    int gg = bidx[n];
    int cnt = gstart[gg + 1] - gstart[gg];
    ls[wave][ch] = v * (1.f / (float)cnt);
    if (ch == 0) gi[wave] = gg;
    __syncthreads();
    if (wave == 0) {
        if (gi[0] == gi[1] && gi[1] == gi[2] && gi[2] == gi[3]) {
            float s = ls[0][ch] + ls[1][ch] + ls[2][ch] + ls[3][ch];
            atomicAdd(&out[gi[0] * CC + ch], s);
        } else {
            #pragma unroll
            for (int w2 = 0; w2 < 4; ++w2)
                atomicAdd(&out[gi[w2] * CC + ch], ls[w2][ch]);
        }
    }
}

extern "C" void kernel_launch(void* const* d_in, const int* in_sizes, int n_in,
                              void* d_out, int out_size, void* d_ws, size_t ws_size,
                              hipStream_t stream) {
    const float* x      = (const float*)d_in[0];
    const float* W1     = (const float*)d_in[1];
    const float* a_src1 = (const float*)d_in[2];
    const float* a_dst1 = (const float*)d_in[3];
    const float* b1     = (const float*)d_in[4];
    const float* Wskip  = (const float*)d_in[5];
    const float* bskip  = (const float*)d_in[6];
    const float* g1     = (const float*)d_in[7];
    const float* be1    = (const float*)d_in[8];
    const float* W2     = (const float*)d_in[9];
    const float* a_src2 = (const float*)d_in[10];
    const float* a_dst2 = (const float*)d_in[11];
    const float* b2     = (const float*)d_in[12];
    const float* g2     = (const float*)d_in[13];
    const float* be2    = (const float*)d_in[14];
    const int*   ei     = (const int*)d_in[15];
    const int*   bidx   = (const int*)d_in[16];
    float* out = (float*)d_out;

    char* w = (char*)d_ws;
    size_t o = 0;
    auto alloc = [&](size_t bytes) -> void* {
        void* p = w + o;
        o = (o + bytes + 255) & ~(size_t)255;
        return p;
    };

    unsigned short* h4b = (unsigned short*)alloc((size_t)NN * HC * 2);  // bf16 [N][C][H]
    float4* es4 = (float4*)alloc((size_t)NN * 16);
    float4* ed4 = (float4*)alloc((size_t)NN * 16);
    float* skip = (float*)alloc((size_t)NN * CC * 4);
    float* gout = (float*)alloc((size_t)NN * CC * 4);
    float* hmid = (float*)alloc((size_t)NN * CC * 4);
    _Float16* BT1 = (_Float16*)alloc((size_t)S1 * FIN * 2);
    _Float16* BT2 = (_Float16*)alloc((size_t)S2 * CC * 2);
    int* csr    = (int*)alloc((size_t)NN * MAXDEG * 4);
    int* gstart = (int*)alloc((size_t)(GG + 1) * 4);
    int* deg      = (int*)alloc((size_t)NN * 4);
    float* sbuck1 = (float*)alloc((size_t)NBUCK * 128 * 4);
    float* sbuck2 = (float*)alloc((size_t)NBUCK * 128 * 4);

    int ebk = (ETOT + 255) / 256;   // 1329
    int nodeblk = NN / 2;           // 10000 (2 nodes/block, 2 waves/node)

    // ---- pre: gbound | BcatT1 | BcatT2 | zero out/deg/sbuck (no memset dispatch) --
    pre1_kernel<<<574, 256, 0, stream>>>(bidx, gstart,
            W1, Wskip, W2, a_src1, a_dst1, a_src2, a_dst2, BT1, BT2,
            deg, sbuck1, sbuck2, out);

    // ---- layer 1 GEMM (1250 blocks) + degree-count+CSR-fill (1329) in one launch --
    gemm_mfma<6><<<1250 + ebk, 256, 0, stream>>>(x, BT1, NN, FIN,
            h4b, skip, (float*)es4, (float*)ed4, 320, 1250, 1, ei, deg, csr);
    // ---- layer 1 aggregation (+bucketed BN stats) ----
    aggr_kernel<<<nodeblk, 256, 0, stream>>>(h4b, es4, ed4, deg, csr, b1, gout,
            sbuck1);

    // ---- layer 2 GEMM with fused BN1+skip+GELU A-staging (writes hmid too) ----
    gemm_mfma_bn<5><<<1250, 256, 0, stream>>>(gout, skip, sbuck1, g1, be1, bskip,
            hmid, BT2, NN, CC, h4b, (float*)es4, (float*)ed4, 256);
    aggr_kernel<<<nodeblk, 256, 0, stream>>>(h4b, es4, ed4, deg, csr, b2, gout,
            sbuck2);
    bnapply2_kernel<<<NN * CC / 256, 256, 0, stream>>>(
        gout, sbuck2, g2, be2, hmid, bidx, gstart, out);
}

// Round 3
// 200.186 us; speedup vs baseline: 3.0517x; 1.1206x over previous
//
#include <hip/hip_runtime.h>
#include <math.h>

#define NN   20000
#define EE   320000
#define ETOT 340000
#define FIN  128
#define HH   4
#define CC   64
#define HC   256
#define GG   64
#define BN_EPS 1e-5f
#define S1   384   // BcatT1 cols: 256 (W1, head-major) + 64 (Wskip) + 8 (es/ed) + 56 pad
#define S2   320   // BcatT2 cols: 256 (W2, head-major) + 8 (es/ed) + 56 pad
#define NBUCK 64   // BN-stats buckets (5000 blocks / 64 ~ 78 adds/address)
#define MAXDEG 64  // fixed-stride CSR row; P(Poisson(16)+1 >= 64) ~ 1e-22, fixed seed

typedef _Float16 v8h __attribute__((ext_vector_type(8)));
typedef _Float16 v4h __attribute__((ext_vector_type(4)));
typedef float    v4f __attribute__((ext_vector_type(4)));

__device__ __forceinline__ unsigned short f2bf(float f) {
    unsigned u = __float_as_uint(f);
    unsigned r = (u + 0x7FFF + ((u >> 16) & 1)) >> 16;   // RNE
    return (unsigned short)r;
}
__device__ __forceinline__ float bf2f(unsigned short u) {
    return __uint_as_float((unsigned)u << 16);
}
__device__ __forceinline__ float gelu_exact(float v) {
    return 0.5f * v * (1.f + erff(v * 0.70710678118654752f));
}

// ====== pre1: gbound | BcatT1 | BcatT2 | zero out/deg/sbuck (510 blocks) ==========
// NOTE: W cols now copied UNPERMUTED (head-major h4b layout): col c -> W[k][c],
// i.e. h4b row = [head][ch]. The aggr read address lane*4 is unchanged; only the
// meaning changes (lane owns head=lane>>4, 4 channels of that head).
__global__ __launch_bounds__(256) void pre1_kernel(
        const int* __restrict__ bidx, int* __restrict__ gstart,
        const float* __restrict__ W1, const float* __restrict__ Wskip,
        const float* __restrict__ W2,
        const float* __restrict__ as1, const float* __restrict__ ad1,
        const float* __restrict__ as2, const float* __restrict__ ad2,
        _Float16* __restrict__ BT1, _Float16* __restrict__ BT2,
        int* __restrict__ deg, float* __restrict__ sbuck1,
        float* __restrict__ sbuck2, float* __restrict__ outz) {
    int b = blockIdx.x, t = threadIdx.x;
    if (b < 79) {
        int i = b * 256 + t;
        if (i >= NN) return;
        int cur = bidx[i];
        if (i == 0) { for (int g = 0; g <= cur; ++g) gstart[g] = 0; }
        else { int prev = bidx[i - 1]; for (int g = prev + 1; g <= cur; ++g) gstart[g] = i; }
        if (i == NN - 1) { for (int g = cur + 1; g <= GG; ++g) gstart[g] = NN; }
    } else if (b < 271) {
        int i = (b - 79) * 256 + t;          // i < S1*FIN = 49152; BT1[col][k]
        int col = i >> 7, k = i & 127;
        float v;
        if (col < 256) {
            v = W1[k * 256 + col];           // head-major (no permutation)
        } else if (col < 320) {
            v = Wskip[k * 64 + (col - 256)];
        } else if (col < 328) {
            int kk = col - 320, h = kk & 3;
            const float* av = (kk < 4 ? as1 : ad1) + h * 64;
            const float* wr = W1 + k * 256 + h * 64;
            float s = 0.f;
            #pragma unroll 8
            for (int c = 0; c < 64; ++c) s += wr[c] * av[c];
            v = s;
        } else v = 0.f;
        BT1[i] = (_Float16)v;
    } else if (b < 351) {
        int i = (b - 271) * 256 + t;         // i < S2*CC = 20480; BT2[col][k]
        int col = i >> 6, k = i & 63;
        float v;
        if (col < 256) {
            v = W2[k * 256 + col];           // head-major (no permutation)
        } else if (col < 264) {
            int kk = col - 256, h = kk & 3;
            const float* av = (kk < 4 ? as2 : ad2) + h * 64;
            const float* wr = W2 + k * 256 + h * 64;
            float s = 0.f;
            #pragma unroll 8
            for (int c = 0; c < 64; ++c) s += wr[c] * av[c];
            v = s;
        } else v = 0.f;
        BT2[i] = (_Float16)v;
    } else if (b < 367) {
        int i = (b - 351) * 256 + t;         // GG*CC = 4096
        outz[i] = 0.f;
    } else if (b < 446) {
        int i = (b - 367) * 256 + t;
        if (i < NN) deg[i] = 0;
    } else if (b < 478) {
        int i = (b - 446) * 256 + t;         // NBUCK*128 = 8192
        sbuck1[i] = 0.f;
    } else {
        int i = (b - 478) * 256 + t;
        sbuck2[i] = 0.f;
    }
}

// ====== fused MFMA fp16 GEMM, 32-row blocks (+ merged count+fill blocks) ==========
template<int NCB>
__global__ __launch_bounds__(256) void gemm_mfma(const float* __restrict__ A,
        const _Float16* __restrict__ BT, int M, int K,
        unsigned short* __restrict__ h4b, float* __restrict__ skipO,
        float* __restrict__ esf, float* __restrict__ edf,
        int escol0, int ngemm, int do_fill,
        const int* __restrict__ ei, int* __restrict__ deg,
        int* __restrict__ csr) {
    int b = blockIdx.x;
    int t = threadIdx.x;
    if (do_fill && b >= ngemm) {
        int i = (b - ngemm) * 256 + t;
        if (i >= ETOT) return;
        int s, d;
        if (i < EE) { s = ei[i]; d = ei[EE + i]; } else { s = i - EE; d = i - EE; }
        int p = atomicAdd(&deg[d], 1);
        if (p < MAXDEG) csr[d * MAXDEG + p] = s;   // overflow never triggers (1e-22)
        return;
    }
    const int COLT = 2 * NCB * 16;         // 192
    __shared__ _Float16 sA[32][40];        // [row][k], 80B rows
    __shared__ _Float16 sBT[2 * NCB * 16][40];
    int tile = b & 1;
    int col0 = tile * COLT;
    int row0 = (b >> 1) * 32;
    int wave = t >> 6, lane = t & 63;
    int l15 = lane & 15, quad = lane >> 4;
    int rb  = wave & 1;                    // row-frag 0/1
    int cb0 = (wave >> 1) * NCB;           // col-frag base
    v4f acc[NCB] = {};
    for (int k0 = 0; k0 < K; k0 += 32) {
        {   // stage A: 32 rows x 32 k, fp32 -> fp16 (one float4 per thread)
            int r = t >> 3, c4 = t & 7;
            int gr = row0 + r;
            float4 v0 = make_float4(0.f, 0.f, 0.f, 0.f);
            if (gr < M) v0 = *(const float4*)&A[(size_t)gr * K + k0 + c4 * 4];
            v4h hv;
            hv[0] = (_Float16)v0.x; hv[1] = (_Float16)v0.y;
            hv[2] = (_Float16)v0.z; hv[3] = (_Float16)v0.w;
            *(v4h*)&sA[r][c4 * 4] = hv;
        }
        for (int j = t; j < COLT * 4; j += 256) {
            int c = j >> 2, s = j & 3;
            *(v8h*)&sBT[c][s * 8] = *(const v8h*)&BT[(size_t)(col0 + c) * K + k0 + s * 8];
        }
        __syncthreads();
        v8h af = *(const v8h*)&sA[rb * 16 + l15][quad * 8];
        #pragma unroll
        for (int c = 0; c < NCB; ++c) {
            v8h bf = *(const v8h*)&sBT[(cb0 + c) * 16 + l15][quad * 8];
            acc[c] = __builtin_amdgcn_mfma_f32_16x16x32_f16(af, bf, acc[c], 0, 0, 0);
        }
        __syncthreads();
    }
    // epilogue: D[row=quad*4+reg][col=l15] per 16x16 frag (verified mapping)
    #pragma unroll
    for (int c = 0; c < NCB; ++c) {
        int gcol = col0 + (cb0 + c) * 16 + l15;
        #pragma unroll
        for (int reg = 0; reg < 4; ++reg) {
            int gr = row0 + rb * 16 + quad * 4 + reg;
            if (gr >= M) continue;
            float v = acc[c][reg];
            if (gcol < 256) {
                h4b[(size_t)gr * HC + gcol] = f2bf(v);
            } else if (skipO != nullptr && gcol < 320) {
                skipO[(size_t)gr * CC + (gcol - 256)] = v;
            } else if (gcol >= escol0 && gcol < escol0 + 8) {
                if (gcol < escol0 + 4) esf[gr * 4 + (gcol - escol0)] = v;
                else                   edf[gr * 4 + (gcol - escol0 - 4)] = v;
            }
        }
    }
}

// ====== layer-2 GEMM with fused BN1+skip+GELU A-staging ===========================
template<int NCB>
__global__ __launch_bounds__(256) void gemm_mfma_bn(const float* __restrict__ gout,
        const float* __restrict__ skip, const float* __restrict__ sbuck,
        const float* __restrict__ g, const float* __restrict__ be,
        const float* __restrict__ bskip, float* __restrict__ hmid,
        const _Float16* __restrict__ BT, int M, int K,
        unsigned short* __restrict__ h4b,
        float* __restrict__ esf, float* __restrict__ edf, int escol0) {
    const int COLT = 2 * NCB * 16;         // 160
    __shared__ _Float16 sA[32][40];
    __shared__ _Float16 sBT[2 * NCB * 16][40];
    __shared__ float tmp[128];
    __shared__ float sscale[64], sshift[64];
    int t = threadIdx.x;
    int b = blockIdx.x;
    if (t < 128) {
        float s = 0.f;
        #pragma unroll 16
        for (int k = 0; k < NBUCK; ++k) s += sbuck[k * 128 + t];
        tmp[t] = s;
    }
    __syncthreads();
    if (t < 64) {
        float mu  = tmp[t] * (1.f / NN);
        float var = tmp[64 + t] * (1.f / NN) - mu * mu;
        float inv = rsqrtf(var + BN_EPS) * g[t];
        sscale[t] = inv;
        sshift[t] = be[t] + bskip[t] - mu * inv;
    }
    __syncthreads();
    int tile = b & 1;
    int col0 = tile * COLT;
    int row0 = (b >> 1) * 32;
    int wave = t >> 6, lane = t & 63;
    int l15 = lane & 15, quad = lane >> 4;
    int rb  = wave & 1;
    int cb0 = (wave >> 1) * NCB;
    v4f acc[NCB] = {};
    for (int k0 = 0; k0 < K; k0 += 32) {
        {   // stage A with fused BN1+skip+GELU: 32 rows x 32 ch, float4/thread
            int r = t >> 3, c4 = t & 7;
            int gr = row0 + r;
            int cb = k0 + c4 * 4;          // channel base
            float vv[4];
            if (gr < M) {
                float4 q = *(const float4*)&gout[(size_t)gr * CC + cb];
                float4 p = *(const float4*)&skip[(size_t)gr * CC + cb];
                float qa[4] = {q.x, q.y, q.z, q.w};
                float pa[4] = {p.x, p.y, p.z, p.w};
                #pragma unroll
                for (int u = 0; u < 4; ++u)
                    vv[u] = gelu_exact(qa[u] * sscale[cb + u] + sshift[cb + u] + pa[u]);
                if (tile == 0)
                    *(float4*)&hmid[(size_t)gr * CC + cb] =
                        make_float4(vv[0], vv[1], vv[2], vv[3]);
            } else {
                vv[0] = vv[1] = vv[2] = vv[3] = 0.f;
            }
            v4h hv;
            hv[0] = (_Float16)vv[0]; hv[1] = (_Float16)vv[1];
            hv[2] = (_Float16)vv[2]; hv[3] = (_Float16)vv[3];
            *(v4h*)&sA[r][c4 * 4] = hv;
        }
        for (int j = t; j < COLT * 4; j += 256) {
            int c = j >> 2, s = j & 3;
            *(v8h*)&sBT[c][s * 8] = *(const v8h*)&BT[(size_t)(col0 + c) * K + k0 + s * 8];
        }
        __syncthreads();
        v8h af = *(const v8h*)&sA[rb * 16 + l15][quad * 8];
        #pragma unroll
        for (int c = 0; c < NCB; ++c) {
            v8h bf = *(const v8h*)&sBT[(cb0 + c) * 16 + l15][quad * 8];
            acc[c] = __builtin_amdgcn_mfma_f32_16x16x32_f16(af, bf, acc[c], 0, 0, 0);
        }
        __syncthreads();
    }
    #pragma unroll
    for (int c = 0; c < NCB; ++c) {
        int gcol = col0 + (cb0 + c) * 16 + l15;
        #pragma unroll
        for (int reg = 0; reg < 4; ++reg) {
            int gr = row0 + rb * 16 + quad * 4 + reg;
            if (gr >= M) continue;
            float v = acc[c][reg];
            if (gcol < 256) {
                h4b[(size_t)gr * HC + gcol] = f2bf(v);
            } else if (gcol >= escol0 && gcol < escol0 + 8) {
                if (gcol < escol0 + 4) esf[gr * 4 + (gcol - escol0)] = v;
                else                   edf[gr * 4 + (gcol - escol0 - 4)] = v;
            }
        }
    }
}

// ====== aggregation + fused BN statistics (head-major: 1 exp/edge/lane) ===========
// grid = NN/4 = 5000 blocks; lane owns head=lane>>4, channels (lane&15)*4..+3.
// Per edge: ONE weight exp (vs 4 in the interleaved layout); head-mean recovered
// with 2 shfl_xor rounds at the end. acc/ssum additive per head -> exact.
__global__ __launch_bounds__(256) void aggr_kernel(const unsigned short* __restrict__ h4b,
        const float* __restrict__ esf, const float* __restrict__ edf,
        const int* __restrict__ deg, const int* __restrict__ csr_src,
        const float* __restrict__ bias, float* __restrict__ out,
        float* __restrict__ sbuck) {
    int wave = threadIdx.x >> 6, lane = threadIdx.x & 63;
    int head = lane >> 4;
    int n = blockIdx.x * 4 + wave;
    float edn = edf[n * 4 + head];
    float4 acc = make_float4(0.f, 0.f, 0.f, 0.f);
    float ssum = 0.f;
    int dn = deg[n];
    dn = (dn < MAXDEG) ? dn : MAXDEG;      // memory safety; never triggers
    int beg = n * MAXDEG, end = beg + dn;
    int j = beg;
    for (; j + 4 <= end; j += 4) {
        int s0 = csr_src[j + 0];
        int s1 = csr_src[j + 1];
        int s2 = csr_src[j + 2];
        int s3 = csr_src[j + 3];
        float E0 = esf[s0 * 4 + head];
        float E1 = esf[s1 * 4 + head];
        float E2 = esf[s2 * 4 + head];
        float E3 = esf[s3 * 4 + head];
        ushort4 v0 = *(const ushort4*)&h4b[(size_t)s0 * HC + lane * 4];
        ushort4 v1 = *(const ushort4*)&h4b[(size_t)s1 * HC + lane * 4];
        ushort4 v2 = *(const ushort4*)&h4b[(size_t)s2 * HC + lane * 4];
        ushort4 v3 = *(const ushort4*)&h4b[(size_t)s3 * HC + lane * 4];
        float e0 = E0 + edn; e0 = fmaxf(e0, 0.2f * e0); float w0 = __expf(e0);
        float e1 = E1 + edn; e1 = fmaxf(e1, 0.2f * e1); float w1 = __expf(e1);
        float e2 = E2 + edn; e2 = fmaxf(e2, 0.2f * e2); float w2 = __expf(e2);
        float e3 = E3 + edn; e3 = fmaxf(e3, 0.2f * e3); float w3 = __expf(e3);
        acc.x += w0 * bf2f(v0.x); acc.y += w0 * bf2f(v0.y);
        acc.z += w0 * bf2f(v0.z); acc.w += w0 * bf2f(v0.w); ssum += w0;
        acc.x += w1 * bf2f(v1.x); acc.y += w1 * bf2f(v1.y);
        acc.z += w1 * bf2f(v1.z); acc.w += w1 * bf2f(v1.w); ssum += w1;
        acc.x += w2 * bf2f(v2.x); acc.y += w2 * bf2f(v2.y);
        acc.z += w2 * bf2f(v2.z); acc.w += w2 * bf2f(v2.w); ssum += w2;
        acc.x += w3 * bf2f(v3.x); acc.y += w3 * bf2f(v3.y);
        acc.z += w3 * bf2f(v3.z); acc.w += w3 * bf2f(v3.w); ssum += w3;
    }
    for (; j < end; ++j) {
        int s = csr_src[j];
        float E = esf[s * 4 + head];
        ushort4 v = *(const ushort4*)&h4b[(size_t)s * HC + lane * 4];
        float e = E + edn; e = fmaxf(e, 0.2f * e); float w = __expf(e);
        acc.x += w * bf2f(v.x); acc.y += w * bf2f(v.y);
        acc.z += w * bf2f(v.z); acc.w += w * bf2f(v.w); ssum += w;
    }
    float inv = 1.f / (ssum + 1e-16f);
    float4 r;
    r.x = acc.x * inv; r.y = acc.y * inv; r.z = acc.z * inv; r.w = acc.w * inv;
    // head-sum: lanes {l, l^16, l^32, l^48} hold the 4 heads of the same channels
    r.x += __shfl_xor(r.x, 16); r.y += __shfl_xor(r.y, 16);
    r.z += __shfl_xor(r.z, 16); r.w += __shfl_xor(r.w, 16);
    r.x += __shfl_xor(r.x, 32); r.y += __shfl_xor(r.y, 32);
    r.z += __shfl_xor(r.z, 32); r.w += __shfl_xor(r.w, 32);
    __shared__ float ls[4][64], lq[4][64];
    if (lane < 16) {
        float4 b4 = *(const float4*)&bias[lane * 4];
        float4 o;
        o.x = 0.25f * r.x + b4.x; o.y = 0.25f * r.y + b4.y;
        o.z = 0.25f * r.z + b4.z; o.w = 0.25f * r.w + b4.w;
        *(float4*)&out[n * CC + lane * 4] = o;
        *(float4*)&ls[wave][lane * 4] = o;
        float4 q;
        q.x = o.x * o.x; q.y = o.y * o.y; q.z = o.z * o.z; q.w = o.w * o.w;
        *(float4*)&lq[wave][lane * 4] = q;
    }
    __syncthreads();
    if (wave == 0) {
        float s = ls[0][lane] + ls[1][lane] + ls[2][lane] + ls[3][lane];
        float q = lq[0][lane] + lq[1][lane] + lq[2][lane] + lq[3][lane];
        int bk = (blockIdx.x & (NBUCK - 1)) * 128;
        atomicAdd(&sbuck[bk + lane], s);
        atomicAdd(&sbuck[bk + 64 + lane], q);
    }
}

// ---------------- BN apply, layer 2 + fused mean-pool (4-node combined atomics) ----
__global__ __launch_bounds__(256) void bnapply2_kernel(const float* __restrict__ gout,
        const float* __restrict__ sbuck, const float* __restrict__ g,
        const float* __restrict__ be, const float* __restrict__ resid,
        const int* __restrict__ bidx, const int* __restrict__ gstart,
        float* __restrict__ out) {
    __shared__ float tmp[128];
    __shared__ float smu[64], sinv[64];
    __shared__ float ls[4][64];
    __shared__ int gi[4];
    int t = threadIdx.x;
    if (t < 128) {
        float s = 0.f;
        #pragma unroll 16
        for (int k = 0; k < NBUCK; ++k) s += sbuck[k * 128 + t];
        tmp[t] = s;
    }
    __syncthreads();
    if (t < 64) {
        float mu  = tmp[t] * (1.f / NN);
        float var = tmp[64 + t] * (1.f / NN) - mu * mu;
        smu[t] = mu;
        sinv[t] = rsqrtf(var + BN_EPS) * g[t];
    }
    __syncthreads();
    int i = blockIdx.x * 256 + t;
    int ch = i & 63;
    int wave = t >> 6;
    int n = i >> 6;
    float v = (gout[i] - smu[ch]) * sinv[ch] + be[ch] + resid[i];
    v = gelu_exact(v);
    int gg = bidx[n];
    int cnt = gstart[gg + 1] - gstart[gg];
    ls[wave][ch] = v * (1.f / (float)cnt);
    if (ch == 0) gi[wave] = gg;
    __syncthreads();
    if (wave == 0) {
        if (gi[0] == gi[1] && gi[1] == gi[2] && gi[2] == gi[3]) {
            float s = ls[0][ch] + ls[1][ch] + ls[2][ch] + ls[3][ch];
            atomicAdd(&out[gi[0] * CC + ch], s);
        } else {
            #pragma unroll
            for (int w2 = 0; w2 < 4; ++w2)
                atomicAdd(&out[gi[w2] * CC + ch], ls[w2][ch]);
        }
    }
}

extern "C" void kernel_launch(void* const* d_in, const int* in_sizes, int n_in,
                              void* d_out, int out_size, void* d_ws, size_t ws_size,
                              hipStream_t stream) {
    const float* x      = (const float*)d_in[0];
    const float* W1     = (const float*)d_in[1];
    const float* a_src1 = (const float*)d_in[2];
    const float* a_dst1 = (const float*)d_in[3];
    const float* b1     = (const float*)d_in[4];
    const float* Wskip  = (const float*)d_in[5];
    const float* bskip  = (const float*)d_in[6];
    const float* g1     = (const float*)d_in[7];
    const float* be1    = (const float*)d_in[8];
    const float* W2     = (const float*)d_in[9];
    const float* a_src2 = (const float*)d_in[10];
    const float* a_dst2 = (const float*)d_in[11];
    const float* b2     = (const float*)d_in[12];
    const float* g2     = (const float*)d_in[13];
    const float* be2    = (const float*)d_in[14];
    const int*   ei     = (const int*)d_in[15];
    const int*   bidx   = (const int*)d_in[16];
    float* out = (float*)d_out;

    char* w = (char*)d_ws;
    size_t o = 0;
    auto alloc = [&](size_t bytes) -> void* {
        void* p = w + o;
        o = (o + bytes + 255) & ~(size_t)255;
        return p;
    };

    unsigned short* h4b = (unsigned short*)alloc((size_t)NN * HC * 2);  // bf16 [N][H][C]
    float* esf = (float*)alloc((size_t)NN * 16);
    float* edf = (float*)alloc((size_t)NN * 16);
    float* skip = (float*)alloc((size_t)NN * CC * 4);
    float* gout = (float*)alloc((size_t)NN * CC * 4);
    float* hmid = (float*)alloc((size_t)NN * CC * 4);
    _Float16* BT1 = (_Float16*)alloc((size_t)S1 * FIN * 2);
    _Float16* BT2 = (_Float16*)alloc((size_t)S2 * CC * 2);
    int* csr    = (int*)alloc((size_t)NN * MAXDEG * 4);
    int* gstart = (int*)alloc((size_t)(GG + 1) * 4);
    int* deg      = (int*)alloc((size_t)NN * 4);
    float* sbuck1 = (float*)alloc((size_t)NBUCK * 128 * 4);
    float* sbuck2 = (float*)alloc((size_t)NBUCK * 128 * 4);

    int ebk = (ETOT + 255) / 256;   // 1329
    int nodeblk = NN / 4;           // 5000 (NN % 4 == 0)

    // ---- pre: gbound | BcatT1 | BcatT2 | zero out/deg/sbuck (no memset dispatch) --
    pre1_kernel<<<510, 256, 0, stream>>>(bidx, gstart,
            W1, Wskip, W2, a_src1, a_dst1, a_src2, a_dst2, BT1, BT2,
            deg, sbuck1, sbuck2, out);

    // ---- layer 1 GEMM (1250 blocks) + degree-count+CSR-fill (1329) in one launch --
    gemm_mfma<6><<<1250 + ebk, 256, 0, stream>>>(x, BT1, NN, FIN,
            h4b, skip, esf, edf, 320, 1250, 1, ei, deg, csr);
    // ---- layer 1 aggregation (+bucketed BN stats) ----
    aggr_kernel<<<nodeblk, 256, 0, stream>>>(h4b, esf, edf, deg, csr, b1, gout,
            sbuck1);

    // ---- layer 2 GEMM with fused BN1+skip+GELU A-staging (writes hmid too) ----
    gemm_mfma_bn<5><<<1250, 256, 0, stream>>>(gout, skip, sbuck1, g1, be1, bskip,
            hmid, BT2, NN, CC, h4b, esf, edf, 256);
    aggr_kernel<<<nodeblk, 256, 0, stream>>>(h4b, esf, edf, deg, csr, b2, gout,
            sbuck2);
    bnapply2_kernel<<<NN * CC / 256, 256, 0, stream>>>(
        gout, sbuck2, g2, be2, hmid, bidx, gstart, out);
}